// Round 14
// baseline (215.761 us; speedup 1.0000x reference)
//
#include <hip/hip_runtime.h>
#include <cstdint>

// B=4096, T=512, I=3, H=32, C=3
#define B_TOT 4096
#define T_LEN 512
#define CHUNK 128
#define LOG2E 1.44269504088896340736f
#define HSTR  40   // hbuf inner stride in halves (80 B)

typedef _Float16 f16x8  __attribute__((ext_vector_type(8)));
typedef _Float16 f16x4  __attribute__((ext_vector_type(4)));
typedef float    f32x4  __attribute__((ext_vector_type(4)));
typedef float    f32x16 __attribute__((ext_vector_type(16)));

__device__ __forceinline__ float ex2(float v)  { return __builtin_amdgcn_exp2f(v); }
__device__ __forceinline__ float rcp_(float v) { return __builtin_amdgcn_rcpf(v); }

// R14: 32x32x16 MFMA, 16-batch tile, 4 waves/block, 256 blocks = 1 block/CU.
// Wave w owns hids [8w,8w+8) = 32 gate-rows. D tile: rows m -> gate=m&3,
// hid=8w+(m>>2); cols = batch (lane&15, cols 16-31 duplicate). K=32 (h dim)
// split into two C-chained mfma_f32_32x32x16_f16 (pipeline at throughput).
// C/D layout (m74/m101): col=lane&31, row=(reg&3)+8*(reg>>2)+4*(lane>>5)
//   => lane holds 4 complete (i,f,g,o) quads, hidx = 2*(reg>>2)+(lane>>5).
// Lane keeps quads 2*sel, 2*sel+1 (sel = bit4 of col): states
//   (batch=col&15, hidA=8w+4*sel+hi) and (…, hidB=hidA+2). 2 states/lane,
//   ZERO extra MFMA duplication (this is what R10/R12 couldn't achieve).
// x-term+bias via third 32x32x16 MFMA: A2 k<3 = W_ih, k=3 = bias (folded
// exp2 scales: sigmoid rows * -log2e, tanh(g) rows * -2log2e); B2 = x pad 1.0.
// Merged-reciprocal gate math: 5 exp2 + 2 rcp per state per step.
__global__ __launch_bounds__(256, 1)
void lstm_32(const float* __restrict__ x,
             const float* __restrict__ W_ih,
             const float* __restrict__ W_hh,
             const float* __restrict__ b_ih,
             const float* __restrict__ b_hh,
             const float* __restrict__ W_fc,
             const float* __restrict__ b_fc,
             float* __restrict__ out)
{
    __shared__ __align__(16) _Float16 hbuf[2][16][HSTR];   // 2.5 KB
    __shared__ __align__(16) _Float16 xbuf[CHUNK][16][4];  // 16 KB

    const int tid  = threadIdx.x;
    const int wave = tid >> 6;        // 0..3
    const int lane = tid & 63;
    const int c    = lane & 31;       // MFMA column / A-B row index
    const int hi   = lane >> 5;
    const int nb   = c & 15;          // my batch
    const int sel  = (c >> 4) & 1;
    const int tb   = blockIdx.x * 16;

    // ---- A fragments: row m = c, k = 8*hi + j ----
    const int   gate_m = c & 3;
    const int   Rm     = gate_m * 32 + 8 * wave + (c >> 2);
    const float sm     = (gate_m == 2) ? (-2.0f * LOG2E) : (-LOG2E);

    f16x8 aK0, aK1;   // W_hh K-halves: k 0..15 and 16..31
#pragma unroll
    for (int j = 0; j < 8; ++j) {
        aK0[j] = (_Float16)(sm * W_hh[Rm * 32 +      8 * hi + j]);
        aK1[j] = (_Float16)(sm * W_hh[Rm * 32 + 16 + 8 * hi + j]);
    }
    f16x8 a2 = {};    // x-weights + bias (k<4, carried by hi==0 lanes)
    if (hi == 0) {
        a2[0] = (_Float16)(sm * W_ih[Rm * 3 + 0]);
        a2[1] = (_Float16)(sm * W_ih[Rm * 3 + 1]);
        a2[2] = (_Float16)(sm * W_ih[Rm * 3 + 2]);
        a2[3] = (_Float16)(sm * (b_ih[Rm] + b_hh[Rm]));
    }

    // my states: (batch nb, hidA) and (batch nb, hidB)
    const int hidA = 8 * wave + 4 * sel + hi;
    const int hidB = hidA + 2;

    // zero h(0) buffer (hbuf[0] = 16*HSTR halves = 320 ints)
    for (int i = tid; i < 320; i += 256) ((int*)&hbuf[0][0][0])[i] = 0;

    const float K2 = -2.0f * LOG2E;
    float cA = 0.0f, cB = 0.0f;
    const f32x16 z = {0.f};
    f32x16 accx;      // x-contribution (incl. bias) for the CURRENT step

    for (int tc = 0; tc < T_LEN; tc += CHUNK) {
        // ---- stage x chunk as fp16, pad slot = 1.0 (bias trick) ----
#pragma unroll
        for (int s = 0; s < 8; ++s) {
            const int idx = tid + s * 256;          // 2048 (t,m) pairs
            const int tl = idx >> 4, m = idx & 15;
            const float* xp = x + ((size_t)(tb + m) * T_LEN + (tc + tl)) * 3;
            f16x4 v;
            v[0] = (_Float16)xp[0]; v[1] = (_Float16)xp[1];
            v[2] = (_Float16)xp[2]; v[3] = (_Float16)1.0f;
            *(f16x4*)&xbuf[tl][m][0] = v;
        }
        __syncthreads();

        {   // accx for first step of chunk
            const f16x4 xv = *(const f16x4*)&xbuf[0][nb][0];
            f16x8 b2 = {};
            if (hi == 0) { b2[0] = xv[0]; b2[1] = xv[1]; b2[2] = xv[2]; b2[3] = xv[3]; }
            accx = __builtin_amdgcn_mfma_f32_32x32x16_f16(a2, b2, z, 0, 0, 0);
        }

#pragma unroll 2
        for (int tt = 0; tt < CHUNK; ++tt) {
            const int p = tt & 1;

            // issue all LDS reads back-to-back (latencies overlap)
            const f16x8 bh0 = *(const f16x8*)&hbuf[p][nb][8 * hi];        // k 0..15
            const f16x8 bh1 = *(const f16x8*)&hbuf[p][nb][16 + 8 * hi];   // k 16..31
            const int ttn = (tt + 1) & (CHUNK - 1);   // wrap -> dummy, recomputed
            const f16x4 xvN = *(const f16x4*)&xbuf[ttn][nb][0];

            // K=32 recurrent matvec: two C-chained 32x32x16 MFMAs
            f32x16 ac = __builtin_amdgcn_mfma_f32_32x32x16_f16(aK0, bh0, accx, 0, 0, 0);
            ac        = __builtin_amdgcn_mfma_f32_32x32x16_f16(aK1, bh1, ac,   0, 0, 0);

            // my two quads: qA = regs [8*sel, +4), qB = regs [8*sel+4, +4)
            const f32x4 q0lo = __builtin_shufflevector(ac, ac, 0, 1, 2, 3);
            const f32x4 q1lo = __builtin_shufflevector(ac, ac, 4, 5, 6, 7);
            const f32x4 q0hi = __builtin_shufflevector(ac, ac, 8, 9, 10, 11);
            const f32x4 q1hi = __builtin_shufflevector(ac, ac, 12, 13, 14, 15);
            const f32x4 qA = sel ? q0hi : q0lo;
            const f32x4 qB = sel ? q1hi : q1lo;

            // ---- state A gate math (merged-reciprocal: 5 exp2 + 2 rcp) ----
            float hA, hB;
            {
                const float ei = ex2(qA[0]), ef = ex2(qA[1]), eg = ex2(qA[2]), eo = ex2(qA[3]);
                const float pi = 1.0f + ei, pf = 1.0f + ef, pg = 1.0f + eg;
                const float mg = 1.0f - eg;
                const float pp = pi * pg, qn = mg * pf;
                cA = fmaf(cA, pp, qn) * rcp_(pf * pp);
                const float ec = ex2(cA * K2);
                const float po = 1.0f + eo, pc = 1.0f + ec, mc = 1.0f - ec;
                hA = mc * rcp_(po * pc);
            }
            // ---- state B (independent -> ILP with A) ----
            {
                const float ei = ex2(qB[0]), ef = ex2(qB[1]), eg = ex2(qB[2]), eo = ex2(qB[3]);
                const float pi = 1.0f + ei, pf = 1.0f + ef, pg = 1.0f + eg;
                const float mg = 1.0f - eg;
                const float pp = pi * pg, qn = mg * pf;
                cB = fmaf(cB, pp, qn) * rcp_(pf * pp);
                const float ec = ex2(cB * K2);
                const float po = 1.0f + eo, pc = 1.0f + ec, mc = 1.0f - ec;
                hB = mc * rcp_(po * pc);
            }

            hbuf[p ^ 1][nb][hidA] = (_Float16)hA;
            hbuf[p ^ 1][nb][hidB] = (_Float16)hB;

            // next step's accx (xvN arrived during trans chain -> pure issue)
            f16x8 b2 = {};
            if (hi == 0) { b2[0] = xvN[0]; b2[1] = xvN[1]; b2[2] = xvN[2]; b2[3] = xvN[3]; }
            accx = __builtin_amdgcn_mfma_f32_32x32x16_f16(a2, b2, z, 0, 0, 0);

            __syncthreads();
        }
    }

    // ---- epilogue: out[tb+m][cc] = b_fc[cc] + sum_k W_fc[cc][k]*h[m][k] ----
    // final h (t=512) is in hbuf[0]; last loop barrier ordered it.
    if (tid < 48) {
        const int m = tid / 3, cc = tid % 3;
        float acc = b_fc[cc];
#pragma unroll
        for (int k = 0; k < 32; ++k)
            acc = fmaf(W_fc[cc * 32 + k], (float)hbuf[0][m][k], acc);
        out[(tb + m) * 3 + cc] = acc;
    }
}

extern "C" void kernel_launch(void* const* d_in, const int* in_sizes, int n_in,
                              void* d_out, int out_size, void* d_ws, size_t ws_size,
                              hipStream_t stream) {
    const float* x    = (const float*)d_in[0];
    const float* W_ih = (const float*)d_in[1];
    const float* W_hh = (const float*)d_in[2];
    const float* b_ih = (const float*)d_in[3];
    const float* b_hh = (const float*)d_in[4];
    const float* W_fc = (const float*)d_in[5];
    const float* b_fc = (const float*)d_in[6];
    float* out = (float*)d_out;

    dim3 grid(B_TOT / 16);   // 256 blocks = 1 per CU
    dim3 block(256);         // 4 waves, 1 wave/SIMD, 2 states/lane
    lstm_32<<<grid, block, 0, stream>>>(x, W_ih, W_hh, b_ih, b_hh, W_fc, b_fc, out);
}

// Round 15
// 188.483 us; speedup vs baseline: 1.1447x; 1.1447x over previous
//
#include <hip/hip_runtime.h>
#include <cstdint>

// B=4096, T=512, I=3, H=32, C=3
#define B_TOT 4096
#define T_LEN 512
#define CHUNK 512            // R15: single staging phase (whole sequence)
#define LOG2E 1.44269504088896340736f
#define HSTR  40             // hbuf inner stride in halves (80 B): 16B-aligned b128

typedef _Float16 f16x8 __attribute__((ext_vector_type(8)));
typedef _Float16 f16x4 __attribute__((ext_vector_type(4)));
typedef float    f32x4 __attribute__((ext_vector_type(4)));

__device__ __forceinline__ float ex2(float v)  { return __builtin_amdgcn_exp2f(v); }
__device__ __forceinline__ float rcp_(float v) { return __builtin_amdgcn_rcpf(v); }

// Measured-optimal family (R5->R8->R13): 8-batch tile, 4 waves/block,
// 512 blocks -> 2 independent barrier domains per CU. Wave w owns hids
// [8w,8w+8) via TWO gate-MFMAs sharing one B fragment (cols = batch n&7, x2):
//   MFMA#1 rows m: gate=m&3, hid=8w+(m>>2); MFMA#2: hid=8w+4+(m>>2)
// Lane (n,kq) state: (batch n&7, hid 8w+kq+(n>=8?4:0)); 1-of-2 select.
// exp2 scales folded into A rows; bias via x-MFMA K-slot 3 (pad staged = 1.0).
// x for two timesteps packed per 16B LDS row -> one ds_read_b128 per 2 steps.
// Merged-reciprocal gate math: 5 exp2 + 2 rcp per state per step.
// R15 deltas: (a) CHUNK=512 -> ONE staging phase for the whole sequence
// (xbuf 32 KB; ~34 KB LDS/block keeps 2 blocks/CU); (b) scaled-c state
// C = -2log2e * c, removing the c*K2 multiply from the serial c->tanh chain
// (K2 folds into the off-chain (1-eg) term).
__global__ __launch_bounds__(256, 2)
void lstm_fin(const float* __restrict__ x,
              const float* __restrict__ W_ih,
              const float* __restrict__ W_hh,
              const float* __restrict__ b_ih,
              const float* __restrict__ b_hh,
              const float* __restrict__ W_fc,
              const float* __restrict__ b_fc,
              float* __restrict__ out)
{
    __shared__ __align__(16) _Float16 hbuf[2][8][HSTR];       // 1.25 KB
    __shared__ __align__(16) _Float16 xbuf[CHUNK / 2][8][8];  // 32 KB: 2 steps/row

    const int tid  = threadIdx.x;
    const int wave = tid >> 6;        // 0..3
    const int lane = tid & 63;
    const int n    = lane & 15;
    const int kq   = lane >> 4;
    const int nb   = n & 7;           // batch column
    const int tb   = blockIdx.x * 8;

    // ---- A-fragment rows (m = n) for the two gate-MFMAs ----
    const int   gate_m = n & 3;
    const int   hl_m   = n >> 2;                       // 0..3
    const int   R1     = gate_m * 32 + 8 * wave + hl_m;
    const int   R2     = R1 + 4;
    const float sm     = (gate_m == 2) ? (-2.0f * LOG2E) : (-LOG2E);

    f16x8 aW1, aW2;
#pragma unroll
    for (int j = 0; j < 8; ++j) {
        aW1[j] = (_Float16)(sm * W_hh[R1 * 32 + 8 * kq + j]);
        aW2[j] = (_Float16)(sm * W_hh[R2 * 32 + 8 * kq + j]);
    }
    f16x8 a21 = {}, a22 = {};         // x-weights + bias (kq==0 lanes carry K 0..3)
    if (kq == 0) {
        a21[0] = (_Float16)(sm * W_ih[R1 * 3 + 0]);
        a21[1] = (_Float16)(sm * W_ih[R1 * 3 + 1]);
        a21[2] = (_Float16)(sm * W_ih[R1 * 3 + 2]);
        a21[3] = (_Float16)(sm * (b_ih[R1] + b_hh[R1]));
        a22[0] = (_Float16)(sm * W_ih[R2 * 3 + 0]);
        a22[1] = (_Float16)(sm * W_ih[R2 * 3 + 1]);
        a22[2] = (_Float16)(sm * W_ih[R2 * 3 + 2]);
        a22[3] = (_Float16)(sm * (b_ih[R2] + b_hh[R2]));
    }

    // my state: (batch nb, hid_s)
    const int hid_s = 8 * wave + kq + ((n >> 3) ? 4 : 0);

    // zero h(0) buffer (hbuf[0] = 8*HSTR halves = 160 ints)
    if (tid < 160) ((int*)&hbuf[0][0][0])[tid] = 0;

    const float K2 = -2.0f * LOG2E;
    float C = 0.0f;                   // scaled cell state: C = K2 * c
    const f32x4 z = {0.f, 0.f, 0.f, 0.f};
    f32x4 accx1, accx2;               // x-contribution (incl. bias), current step

    const bool hi = (n >> 3) != 0;

    // ---- stage the ENTIRE x sequence as fp16 pairs (one phase):
    //      row [t>>1][m] holds steps t,t+1; pad slot = 1.0 (bias trick) ----
#pragma unroll
    for (int s = 0; s < 16; ++s) {
        const int idx = tid + s * 256;          // 4096 (t,m) pairs
        const int tl = idx >> 3, m = idx & 7;
        const float* xp = x + ((size_t)(tb + m) * T_LEN + tl) * 3;
        f16x4 v;
        v[0] = (_Float16)xp[0]; v[1] = (_Float16)xp[1];
        v[2] = (_Float16)xp[2]; v[3] = (_Float16)1.0f;
        *(f16x4*)&xbuf[tl >> 1][m][4 * (tl & 1)] = v;
    }
    __syncthreads();

    // first pair + accx for step 0
    f16x8 xp = *(const f16x8*)&xbuf[0][nb][0];
    {
        const f16x8 b2 = __builtin_shufflevector(xp, xp, 0, 1, 2, 3, 0, 1, 2, 3);
        accx1 = __builtin_amdgcn_mfma_f32_16x16x32_f16(a21, b2, z, 0, 0, 0);
        accx2 = __builtin_amdgcn_mfma_f32_16x16x32_f16(a22, b2, z, 0, 0, 0);
    }

    for (int t2 = 0; t2 < CHUNK / 2; ++t2) {
        // ================= even step (parity 0) =================
        {
            const f16x8 bh = *(const f16x8*)&hbuf[0][nb][8 * kq];
            const f32x4 ac1 = __builtin_amdgcn_mfma_f32_16x16x32_f16(aW1, bh, accx1, 0, 0, 0);
            const f32x4 ac2 = __builtin_amdgcn_mfma_f32_16x16x32_f16(aW2, bh, accx2, 0, 0, 0);

            const float a0 = hi ? ac2[0] : ac1[0];
            const float a1 = hi ? ac2[1] : ac1[1];
            const float a2 = hi ? ac2[2] : ac1[2];
            const float a3 = hi ? ac2[3] : ac1[3];

            const float ei = ex2(a0), ef = ex2(a1), eg = ex2(a2), eo = ex2(a3);
            const float pi = 1.0f + ei, pf = 1.0f + ef, pg = 1.0f + eg;
            const float mg2 = fmaf(-K2, eg, K2);          // K2*(1-eg), off-chain
            const float pp = pi * pg, qn2 = mg2 * pf;
            C = fmaf(C, pp, qn2) * rcp_(pf * pp);         // scaled-c update
            const float ec = ex2(C);                      // = exp2(K2*c)
            const float po = 1.0f + eo, pc = 1.0f + ec, mc = 1.0f - ec;
            const float h = mc * rcp_(po * pc);
            hbuf[1][nb][hid_s] = (_Float16)h;

            // accx for the odd step from the pair's hi half (data in regs)
            const f16x8 b2 = __builtin_shufflevector(xp, xp, 4, 5, 6, 7, 4, 5, 6, 7);
            accx1 = __builtin_amdgcn_mfma_f32_16x16x32_f16(a21, b2, z, 0, 0, 0);
            accx2 = __builtin_amdgcn_mfma_f32_16x16x32_f16(a22, b2, z, 0, 0, 0);
        }
        __syncthreads();

        // ================= odd step (parity 1) =================
        {
            // issue h-read and next pair's x-read back-to-back
            const f16x8 bh = *(const f16x8*)&hbuf[1][nb][8 * kq];
            const int t2n = (t2 + 1) & (CHUNK / 2 - 1);   // wrap -> dummy
            const f16x8 xpN = *(const f16x8*)&xbuf[t2n][nb][0];

            const f32x4 ac1 = __builtin_amdgcn_mfma_f32_16x16x32_f16(aW1, bh, accx1, 0, 0, 0);
            const f32x4 ac2 = __builtin_amdgcn_mfma_f32_16x16x32_f16(aW2, bh, accx2, 0, 0, 0);

            const float a0 = hi ? ac2[0] : ac1[0];
            const float a1 = hi ? ac2[1] : ac1[1];
            const float a2 = hi ? ac2[2] : ac1[2];
            const float a3 = hi ? ac2[3] : ac1[3];

            const float ei = ex2(a0), ef = ex2(a1), eg = ex2(a2), eo = ex2(a3);
            const float pi = 1.0f + ei, pf = 1.0f + ef, pg = 1.0f + eg;
            const float mg2 = fmaf(-K2, eg, K2);
            const float pp = pi * pg, qn2 = mg2 * pf;
            C = fmaf(C, pp, qn2) * rcp_(pf * pp);
            const float ec = ex2(C);
            const float po = 1.0f + eo, pc = 1.0f + ec, mc = 1.0f - ec;
            const float h = mc * rcp_(po * pc);
            hbuf[0][nb][hid_s] = (_Float16)h;

            // accx for next even step from xpN's lo half
            const f16x8 b2 = __builtin_shufflevector(xpN, xpN, 0, 1, 2, 3, 0, 1, 2, 3);
            accx1 = __builtin_amdgcn_mfma_f32_16x16x32_f16(a21, b2, z, 0, 0, 0);
            accx2 = __builtin_amdgcn_mfma_f32_16x16x32_f16(a22, b2, z, 0, 0, 0);
            xp = xpN;
        }
        __syncthreads();
    }

    // ---- epilogue: out[tb+m][cc] = b_fc[cc] + sum_k W_fc[cc][k]*h[m][k] ----
    // final h (t=512) is in hbuf[0]; last loop barrier ordered it.
    if (tid < 24) {
        const int m = tid / 3, cc = tid % 3;
        float acc = b_fc[cc];
#pragma unroll
        for (int k = 0; k < 32; ++k)
            acc = fmaf(W_fc[cc * 32 + k], (float)hbuf[0][m][k], acc);
        out[(tb + m) * 3 + cc] = acc;
    }
}

extern "C" void kernel_launch(void* const* d_in, const int* in_sizes, int n_in,
                              void* d_out, int out_size, void* d_ws, size_t ws_size,
                              hipStream_t stream) {
    const float* x    = (const float*)d_in[0];
    const float* W_ih = (const float*)d_in[1];
    const float* W_hh = (const float*)d_in[2];
    const float* b_ih = (const float*)d_in[3];
    const float* b_hh = (const float*)d_in[4];
    const float* W_fc = (const float*)d_in[5];
    const float* b_fc = (const float*)d_in[6];
    float* out = (float*)d_out;

    dim3 grid(B_TOT / 8);    // 512 blocks -> 2 independent barrier domains per CU
    dim3 block(256);         // 4 waves, 8 hids/wave
    lstm_fin<<<grid, block, 0, stream>>>(x, W_ih, W_hh, b_ih, b_hh, W_fc, b_fc, out);
}